// Round 6
// baseline (320.393 us; speedup 1.0000x reference)
//
#include <hip/hip_runtime.h>
#include <hip/hip_bf16.h>

// Confusion-classification criterion (see reference):
//   pred = argmax(pred_logits[...,0:2])            (tie -> index 0)
//   cls  = g==1 ? (pred ? 1 : 2) : (pred ? 3 : 0)  (TP=1 FN=2 FP=3 TN=0)
//   loss = mean over B*N of -log_softmax(pred_confusion)[cls]
//
// R5 -> R6: single dispatch. Last-block-done reduction replaces the second
// kernel. The done-counter lives in d_ws, which the harness poisons to
// 0xAAAAAAAA before every launch — increments from there are deterministic,
// so the block seeing old == 0xAAAAAAAA + grid-1 is the last one. Device
// fences around the counter give release/acquire across XCDs (G16).

#define NPART 4096
#define K_ELEMS 4
#define POISON_U32 0xAAAAAAAAu

__device__ __forceinline__ float nll_one(float4 c, bool gpos, bool pred)
{
    int cls = gpos ? (pred ? 1 : 2) : (pred ? 3 : 0);
    float m   = fmaxf(fmaxf(c.x, c.y), fmaxf(c.z, c.w));
    float s   = __expf(c.x - m) + __expf(c.y - m) +
                __expf(c.z - m) + __expf(c.w - m);
    float lse = m + __logf(s);
    float xc  = (cls == 0) ? c.x : (cls == 1) ? c.y : (cls == 2) ? c.z : c.w;
    return lse - xc;
}

__global__ __launch_bounds__(256) void confusion_loss_kernel(
    const float2* __restrict__ lg,    // [total] logit pairs
    const float4* __restrict__ conf,  // [total] confusion rows
    const int*    __restrict__ tg,    // [total] targets
    float*        __restrict__ partials, // [NPART] in d_ws
    unsigned int* __restrict__ done,     // [1] in d_ws, poison-initialized
    float*        __restrict__ out,      // [1]
    int total, float inv_total)
{
    const int tid   = threadIdx.x;
    const int bdim  = blockDim.x;
    const int chunk = bdim * K_ELEMS;

    float acc = 0.0f;
    for (int base = blockIdx.x * chunk; base < total;
         base += gridDim.x * chunk) {

        if (base + chunk <= total) {
            float4 c[K_ELEMS];
            float2 l[K_ELEMS];
            int    g[K_ELEMS];
            #pragma unroll
            for (int k = 0; k < K_ELEMS; ++k) {
                int e = base + k * bdim + tid;
                c[k] = conf[e];
                l[k] = lg[e];
                g[k] = tg[e];
            }
            #pragma unroll
            for (int k = 0; k < K_ELEMS; ++k)
                acc += nll_one(c[k], g[k] == 1, l[k].y > l[k].x);
        } else {
            for (int k = 0; k < K_ELEMS; ++k) {
                int e = base + k * bdim + tid;
                if (e < total) {
                    float2 l = lg[e];
                    acc += nll_one(conf[e], tg[e] == 1, l.y > l.x);
                }
            }
        }
    }

    // wave-64 reduce
    #pragma unroll
    for (int off = 32; off > 0; off >>= 1)
        acc += __shfl_down(acc, off, 64);

    __shared__ float wsum[4];
    __shared__ bool  amLast;
    int lane = tid & 63;
    int wid  = tid >> 6;
    if (lane == 0) wsum[wid] = acc;
    __syncthreads();

    if (tid == 0) {
        partials[blockIdx.x] = wsum[0] + wsum[1] + wsum[2] + wsum[3];
        __threadfence();                         // release: partial visible
        unsigned int old = atomicAdd(done, 1u);  // device-scope
        amLast = (old == POISON_U32 + (unsigned)gridDim.x - 1u);
    }
    __syncthreads();

    if (amLast) {
        __threadfence();                         // acquire: see all partials
        const float4* p4 = (const float4*)partials;
        float facc = 0.0f;
        for (int i = tid; i < NPART / 4; i += bdim) {
            float4 p = p4[i];
            facc += (p.x + p.y) + (p.z + p.w);
        }
        #pragma unroll
        for (int off = 32; off > 0; off >>= 1)
            facc += __shfl_down(facc, off, 64);
        if (lane == 0) wsum[wid] = facc;
        __syncthreads();
        if (tid == 0)
            out[0] = (wsum[0] + wsum[1] + wsum[2] + wsum[3]) * inv_total;
    }
}

extern "C" void kernel_launch(void* const* d_in, const int* in_sizes, int n_in,
                              void* d_out, int out_size, void* d_ws, size_t ws_size,
                              hipStream_t stream)
{
    const float2* lg    = (const float2*)d_in[0];
    const float4* conf  = (const float4*)d_in[1];
    const int*    tg    = (const int*)d_in[2];
    float*        out   = (float*)d_out;
    float*        parts = (float*)d_ws;                 // NPART floats
    unsigned int* done  = (unsigned int*)((char*)d_ws + NPART * sizeof(float));

    const int total = in_sizes[2];                      // B*N = 4,194,304

    confusion_loss_kernel<<<NPART, 256, 0, stream>>>(
        lg, conf, tg, parts, done, out, total, 1.0f / (float)total);
}

// Round 7
// 135.721 us; speedup vs baseline: 2.3607x; 2.3607x over previous
//
#include <hip/hip_runtime.h>
#include <hip/hip_bf16.h>

// Confusion-classification criterion (see reference):
//   pred = argmax(pred_logits[...,0:2])            (tie -> index 0)
//   cls  = g==1 ? (pred ? 1 : 2) : (pred ? 3 : 0)  (TP=1 FN=2 FP=3 TN=0)
//   loss = mean over B*N of -log_softmax(pred_confusion)[cls]
//
// R6 -> R7: REVERT to R5 (best: 135.2 us). The single-dispatch last-block
// reduction (R6) regressed 2.4x: per-block __threadfence() emits L2
// writeback/invalidate cache-ops; 4096 of them serialize the TCC pipeline
// (hbm_gbps 4000+ -> 259). Two-kernel reduction gets cross-XCD ordering
// free from the dispatch boundary — keep it.

#define NPART 4096
#define K_ELEMS 4

__device__ __forceinline__ float nll_one(float4 c, bool gpos, bool pred)
{
    int cls = gpos ? (pred ? 1 : 2) : (pred ? 3 : 0);
    float m   = fmaxf(fmaxf(c.x, c.y), fmaxf(c.z, c.w));
    float s   = __expf(c.x - m) + __expf(c.y - m) +
                __expf(c.z - m) + __expf(c.w - m);
    float lse = m + __logf(s);
    float xc  = (cls == 0) ? c.x : (cls == 1) ? c.y : (cls == 2) ? c.z : c.w;
    return lse - xc;
}

__global__ __launch_bounds__(256) void confusion_part_kernel(
    const float2* __restrict__ lg,    // [total] logit pairs
    const float4* __restrict__ conf,  // [total] confusion rows
    const int*    __restrict__ tg,    // [total] targets
    float* __restrict__ partials,     // [NPART]
    int total)
{
    const int tid   = threadIdx.x;
    const int bdim  = blockDim.x;
    const int chunk = bdim * K_ELEMS;              // elements per block-pass

    float acc = 0.0f;
    for (int base = blockIdx.x * chunk; base < total;
         base += gridDim.x * chunk) {

        if (base + chunk <= total) {
            // full tile: issue all coalesced loads first
            float4 c[K_ELEMS];
            float2 l[K_ELEMS];
            int    g[K_ELEMS];
            #pragma unroll
            for (int k = 0; k < K_ELEMS; ++k) {
                int e = base + k * bdim + tid;
                c[k] = conf[e];
                l[k] = lg[e];
                g[k] = tg[e];
            }
            #pragma unroll
            for (int k = 0; k < K_ELEMS; ++k)
                acc += nll_one(c[k], g[k] == 1, l[k].y > l[k].x);
        } else {
            // ragged tail tile (not hit at B*N = 4,194,304)
            for (int k = 0; k < K_ELEMS; ++k) {
                int e = base + k * bdim + tid;
                if (e < total) {
                    float2 l = lg[e];
                    acc += nll_one(conf[e], tg[e] == 1, l.y > l.x);
                }
            }
        }
    }

    // wave-64 reduce
    #pragma unroll
    for (int off = 32; off > 0; off >>= 1)
        acc += __shfl_down(acc, off, 64);

    __shared__ float wsum[4];
    int lane = tid & 63;
    int wid  = tid >> 6;
    if (lane == 0) wsum[wid] = acc;
    __syncthreads();

    if (tid == 0)
        partials[blockIdx.x] = wsum[0] + wsum[1] + wsum[2] + wsum[3];
}

__global__ __launch_bounds__(256) void confusion_final_kernel(
    const float4* __restrict__ partials, float* __restrict__ out,
    int nquads, float inv_total)
{
    float acc = 0.0f;
    for (int i = threadIdx.x; i < nquads; i += 256) {
        float4 p = partials[i];
        acc += (p.x + p.y) + (p.z + p.w);
    }

    #pragma unroll
    for (int off = 32; off > 0; off >>= 1)
        acc += __shfl_down(acc, off, 64);

    __shared__ float wsum[4];
    int lane = threadIdx.x & 63;
    int wid  = threadIdx.x >> 6;
    if (lane == 0) wsum[wid] = acc;
    __syncthreads();

    if (threadIdx.x == 0)
        out[0] = (wsum[0] + wsum[1] + wsum[2] + wsum[3]) * inv_total;
}

extern "C" void kernel_launch(void* const* d_in, const int* in_sizes, int n_in,
                              void* d_out, int out_size, void* d_ws, size_t ws_size,
                              hipStream_t stream)
{
    const float2* lg    = (const float2*)d_in[0];
    const float4* conf  = (const float4*)d_in[1];
    const int*    tg    = (const int*)d_in[2];
    float*        out   = (float*)d_out;
    float*        parts = (float*)d_ws;       // NPART floats (16 KB)

    const int total = in_sizes[2];            // B*N = 4,194,304

    confusion_part_kernel<<<NPART, 256, 0, stream>>>(
        lg, conf, tg, parts, total);
    confusion_final_kernel<<<1, 256, 0, stream>>>(
        (const float4*)parts, out, NPART / 4, 1.0f / (float)total);
}